// Round 6
// baseline (2138.860 us; speedup 1.0000x reference)
//
#include <hip/hip_runtime.h>

typedef __attribute__((ext_vector_type(8)))  short short8;
typedef __attribute__((ext_vector_type(16))) float f32x16;

#define NPTS 2048
#define BATCH 32
#define NUM_CLASSES 6
#define THREADS 256
#define CC 2                  // candidate chunks per (dir,batch)
#define CANDS_BLK 1024        // NPTS / CC
#define QC 16                 // query chunks of 128
#define BF16_ONE ((short)0x3F80)
// grid1 = 2 * 32 * QC * CC = 2048 blocks
// ws: pmin[64][QC][CC][128] floats (64*4096), then partial[64]
#define PART_OFF (64 * 4096)

__device__ __forceinline__ unsigned short f2bf(float x) {
    union { float f; unsigned u; } v; v.f = x;
    unsigned r = v.u + 0x7FFF + ((v.u >> 16) & 1);   // RNE to bf16
    return (unsigned short)(r >> 16);
}
__device__ __forceinline__ float bf2f(unsigned short h) {
    union { unsigned u; float f; } v; v.u = ((unsigned)h) << 16; return v.f;
}
template<int CTRL>
__device__ __forceinline__ float dpp_ror_min(float v) {
    union { float f; int i; } a, r;
    a.f = v;
    r.i = __builtin_amdgcn_update_dpp(a.i, a.i, CTRL, 0xF, 0xF, false);
    return fminf(v, r.f);
}

// K-slot plan (K=16): D = a2 + b2 - 2 a.b (hi/lo bf16 split):
//  k0-2: A=ah B=-2bh | k3-5: A=al B=-2bh | k6-8: A=ah B=-2bl
//  k9: A=1 B=b2h | k10: A=1 B=b2l | k11: A=a2h B=1 | k12: A=a2l B=1 | k13-15: 0
__global__ __launch_bounds__(THREADS, 4) void chamfer_pass1(
    const float* __restrict__ inst, const float* __restrict__ model,
    float* __restrict__ ws)
{
    __shared__ char cands[CANDS_BLK * 32];   // 32 KB

    const int blk   = blockIdx.x;
    const int cc    = blk & 1;
    const int qc    = (blk >> 1) & 15;
    const int batch = (blk >> 5) & 31;
    const int dir   = blk >> 10;
    const int tid   = threadIdx.x;
    const int lane  = tid & 63, wid = tid >> 6;
    const int lh    = lane >> 5, lr = lane & 31;

    const float* __restrict__ Q  = dir ? model : inst;
    const float* __restrict__ Cp = dir ? inst  : model;

    // ---- stage 1024 candidates into B-frag layout ----
    const float* cb = Cp + ((size_t)batch * NPTS + (size_t)cc * CANDS_BLK) * 3;
    #pragma unroll
    for (int k = 0; k < CANDS_BLK / THREADS; ++k) {
        const int c = tid + k * THREADS;
        float bx = cb[c*3+0], by = cb[c*3+1], bz = cb[c*3+2];
        float m2x = -2.f*bx, m2y = -2.f*by, m2z = -2.f*bz;
        unsigned short hx = f2bf(m2x), hy = f2bf(m2y), hz = f2bf(m2z);
        unsigned short lx = f2bf(m2x - bf2f(hx));
        unsigned short ly = f2bf(m2y - bf2f(hy));
        unsigned short lz = f2bf(m2z - bf2f(hz));
        float b2 = fmaf(bx,bx, fmaf(by,by, bz*bz));
        unsigned short b2h = f2bf(b2);
        unsigned short b2l = f2bf(b2 - bf2f(b2h));
        short8 kg0 = { (short)hx,(short)hy,(short)hz,(short)hx,(short)hy,(short)hz,(short)lx,(short)ly };
        short8 kg1 = { (short)lz,(short)b2h,(short)b2l, BF16_ONE, BF16_ONE, 0,0,0 };
        *(short8*)(cands + c*32)      = kg0;
        *(short8*)(cands + c*32 + 16) = kg1;
    }

    // ---- A-frag: 32 queries per wave (row = lane&31, k = (lane>>5)*8 + j) ----
    short8 af;
    {
        const float* qb = Q + ((size_t)batch * NPTS + (size_t)qc * 128) * 3;
        const int qi = wid * 32 + lr;
        float x = qb[qi*3+0], y = qb[qi*3+1], z = qb[qi*3+2];
        unsigned short hx = f2bf(x), hy = f2bf(y), hz = f2bf(z);
        unsigned short lx = f2bf(x - bf2f(hx));
        unsigned short ly = f2bf(y - bf2f(hy));
        unsigned short lz = f2bf(z - bf2f(hz));
        float a2 = fmaf(x,x, fmaf(y,y, z*z));
        unsigned short a2h = f2bf(a2);
        unsigned short a2l = f2bf(a2 - bf2f(a2h));
        if (lh == 0)
            af = (short8){ (short)hx,(short)hy,(short)hz,(short)lx,(short)ly,(short)lz,(short)hx,(short)hy };
        else
            af = (short8){ (short)hz, BF16_ONE, BF16_ONE, (short)a2h,(short)a2l, 0,0,0 };
    }
    __syncthreads();

    // ---- main loop: 32 tiles, 2/iter; B read conflict-free; min3 fold ----
    f32x16 mn, zero16;
    #pragma unroll
    for (int r = 0; r < 16; ++r) { mn[r] = 3.4e38f; zero16[r] = 0.f; }

    int boff = lr * 32 + lh * 16;
    for (int it = 0; it < 16; ++it) {
        short8 b0 = *(const short8*)(cands + boff);
        short8 b1 = *(const short8*)(cands + boff + 1024);
        boff += 2048;
        f32x16 a0 = __builtin_amdgcn_mfma_f32_32x32x16_bf16(af, b0, zero16, 0,0,0);
        f32x16 a1 = __builtin_amdgcn_mfma_f32_32x32x16_bf16(af, b1, zero16, 0,0,0);
        #pragma unroll
        for (int r = 0; r < 16; ++r) mn[r] = fminf(mn[r], fminf(a0[r], a1[r]));  // v_min3
    }

    // ---- epilogue: 32-lane col-min via DPP ror (VALU) + one xor16 swizzle ----
    // D layout: col = lane&31, row = (r&3) + 8*(r>>2) + 4*lh
    const int db = dir * BATCH + batch;
    float* pmin = ws + (size_t)db * 4096 + qc * (CC * 128) + cc * 128 + wid * 32;
    #pragma unroll
    for (int r = 0; r < 16; ++r) {
        float v = mn[r];
        v = dpp_ror_min<0x128>(v);   // row_ror:8
        v = dpp_ror_min<0x124>(v);   // row_ror:4
        v = dpp_ror_min<0x122>(v);   // row_ror:2
        v = dpp_ror_min<0x121>(v);   // row_ror:1
        {   // min with lane^16 partner (within each 32-group)
            union { float f; int i; } a, s;
            a.f = v; s.i = __builtin_amdgcn_ds_swizzle(a.i, 0x401F);
            v = fminf(v, s.f);
        }
        if (lr == 0) pmin[(r & 3) + 8 * (r >> 2) + 4 * lh] = v;
    }
}

// ---- kernel 2: min across CC chunks, sum per (dir,batch) -------------------
__global__ __launch_bounds__(256) void combine_kernel(
    const float* __restrict__ ws, float* __restrict__ partial)
{
    const int db  = blockIdx.x;       // 0..63
    const int tid = threadIdx.x;
    const float* base = ws + (size_t)db * 4096;

    float s = 0.f;
    #pragma unroll
    for (int k = 0; k < 8; ++k) {
        const int q   = k * 256 + tid;            // 0..2047
        const int idx = (q >> 7) * 256 + (q & 127);
        s += fminf(base[idx], base[idx + 128]);
    }
    #pragma unroll
    for (int o = 32; o > 0; o >>= 1) s += __shfl_down(s, o, 64);
    __shared__ float wsum[4];
    const int lane = tid & 63, wid = tid >> 6;
    if (lane == 0) wsum[wid] = s;
    __syncthreads();
    if (tid == 0) partial[db] = (wsum[0] + wsum[1]) + (wsum[2] + wsum[3]);
}

// ---- kernel 3: 64-sum + cross-entropy + output -----------------------------
__global__ __launch_bounds__(64) void finalize_kernel(
    const float* __restrict__ partial, const float* __restrict__ pred,
    const int* __restrict__ gt, float* __restrict__ out)
{
    const int tid = threadIdx.x;
    __shared__ float s_ce[BATCH];

    float v = partial[tid];
    #pragma unroll
    for (int o = 32; o > 0; o >>= 1) v += __shfl_down(v, o, 64);
    // lane0 now has total cd sum

    if (tid < BATCH) {
        const float* row = pred + tid * NUM_CLASSES;
        float mx = row[0];
        #pragma unroll
        for (int c = 1; c < NUM_CLASSES; ++c) mx = fmaxf(mx, row[c]);
        float se = 0.f;
        #pragma unroll
        for (int c = 0; c < NUM_CLASSES; ++c) se += __expf(row[c] - mx);
        const int lbl = gt[tid];
        s_ce[tid] = -(row[lbl] - mx - __logf(se));
    }
    __syncthreads();

    if (tid == 0) {
        float cd = v / (float)(BATCH * NPTS);
        float ce = 0.f;
        for (int i = 0; i < BATCH; ++i) ce += s_ce[i];
        ce /= (float)BATCH;
        out[0] = 5.f * cd + ce;
        out[1] = cd;
        out[2] = ce;
    }
}

extern "C" void kernel_launch(void* const* d_in, const int* in_sizes, int n_in,
                              void* d_out, int out_size, void* d_ws, size_t ws_size,
                              hipStream_t stream) {
    const float* inst  = (const float*)d_in[0];
    const float* model = (const float*)d_in[1];
    const float* pred  = (const float*)d_in[2];
    const int*   gt    = (const int*)d_in[3];
    float* out = (float*)d_out;
    float* ws  = (float*)d_ws;
    float* partial = ws + PART_OFF;

    chamfer_pass1<<<2 * BATCH * QC * CC, THREADS, 0, stream>>>(inst, model, ws);
    combine_kernel<<<64, 256, 0, stream>>>(ws, partial);
    finalize_kernel<<<1, 64, 0, stream>>>(partial, pred, gt, out);
}

// Round 7
// 31.373 us; speedup vs baseline: 68.1748x; 68.1748x over previous
//
#include <hip/hip_runtime.h>

typedef __attribute__((ext_vector_type(8)))  short short8;
typedef __attribute__((ext_vector_type(16))) float f32x16;

#define NPTS 2048
#define BATCH 32
#define NUM_CLASSES 6
#define THREADS 256
#define CC 4                 // candidate chunks per (dir,batch)
#define CANDS_BLK 512        // NPTS / CC
#define QC 8                 // query chunks of 256
#define GROUPS 512           // 2 * 32 * 8
#define BF16_ONE ((short)0x3F80)
// ws: pmin[GROUPS][CC][256] floats, then partial[64]
#define PART_OFF (GROUPS * CC * 256)

__device__ __forceinline__ unsigned short f2bf(float x) {
    union { float f; unsigned u; } v; v.f = x;
    unsigned r = v.u + 0x7FFF + ((v.u >> 16) & 1);   // RNE to bf16
    return (unsigned short)(r >> 16);
}
__device__ __forceinline__ float bf2f(unsigned short h) {
    union { unsigned u; float f; } v; v.u = ((unsigned)h) << 16; return v.f;
}

// K-slot plan (K=16): D = a2 + b2 - 2 a.b (hi/lo bf16 split, absmax-0 verified):
//  k0-2: A=ah B=-2bh | k3-5: A=al B=-2bh | k6-8: A=ah B=-2bl
//  k9: A=1 B=b2h | k10: A=1 B=b2l | k11: A=a2h B=1 | k12: A=a2l B=1 | k13-15: 0
__global__ __launch_bounds__(THREADS, 4) void chamfer_pass1(
    const float* __restrict__ inst, const float* __restrict__ model,
    float* __restrict__ ws)
{
    __shared__ char cands[CANDS_BLK * 32];   // 16 KB
    const int blk   = blockIdx.x;
    const int cc    = blk & 3;
    const int qc    = (blk >> 2) & 7;
    const int batch = (blk >> 5) & 31;
    const int dir   = blk >> 10;
    const int g     = (dir * BATCH + batch) * QC + qc;
    const int tid   = threadIdx.x;
    const int lane  = tid & 63, wid = tid >> 6;
    const int lh    = lane >> 5, lr = lane & 31;

    const float* __restrict__ Q  = dir ? model : inst;
    const float* __restrict__ Cp = dir ? inst  : model;

    // ---- stage this block's 512 candidates into B-frag layout ----
    const float* cb = Cp + ((size_t)batch * NPTS + (size_t)cc * CANDS_BLK) * 3;
    for (int c = tid; c < CANDS_BLK; c += THREADS) {
        float bx = cb[c*3+0], by = cb[c*3+1], bz = cb[c*3+2];
        float m2x = -2.f*bx, m2y = -2.f*by, m2z = -2.f*bz;
        unsigned short hx = f2bf(m2x), hy = f2bf(m2y), hz = f2bf(m2z);
        unsigned short lx = f2bf(m2x - bf2f(hx));
        unsigned short ly = f2bf(m2y - bf2f(hy));
        unsigned short lz = f2bf(m2z - bf2f(hz));
        float b2 = fmaf(bx,bx, fmaf(by,by, bz*bz));
        unsigned short b2h = f2bf(b2);
        unsigned short b2l = f2bf(b2 - bf2f(b2h));
        short8 kg0 = { (short)hx,(short)hy,(short)hz,(short)hx,(short)hy,(short)hz,(short)lx,(short)ly };
        short8 kg1 = { (short)lz,(short)b2h,(short)b2l, BF16_ONE, BF16_ONE, 0,0,0 };
        *(short8*)(cands + c*32)      = kg0;
        *(short8*)(cands + c*32 + 16) = kg1;
    }

    // ---- A-frags (row = lane&31, k = (lane>>5)*8 + j), 64 queries per wave ----
    short8 af[2];
    const float* qb = Q + ((size_t)batch * NPTS + (size_t)qc * 256) * 3;
    #pragma unroll
    for (int qt = 0; qt < 2; ++qt) {
        const int qi = (wid * 2 + qt) * 32 + lr;
        float x = qb[qi*3+0], y = qb[qi*3+1], z = qb[qi*3+2];
        unsigned short hx = f2bf(x), hy = f2bf(y), hz = f2bf(z);
        unsigned short lx = f2bf(x - bf2f(hx));
        unsigned short ly = f2bf(y - bf2f(hy));
        unsigned short lz = f2bf(z - bf2f(hz));
        float a2 = fmaf(x,x, fmaf(y,y, z*z));
        unsigned short a2h = f2bf(a2);
        unsigned short a2l = f2bf(a2 - bf2f(a2h));
        if (lh == 0)
            af[qt] = (short8){ (short)hx,(short)hy,(short)hz,(short)lx,(short)ly,(short)lz,(short)hx,(short)hy };
        else
            af[qt] = (short8){ (short)hz, BF16_ONE, BF16_ONE, (short)a2h,(short)a2l, 0,0,0 };
    }
    __syncthreads();

    // ---- main loop: 16 candidate tiles, 2 mfma each (R5-verified, no spill) ----
    f32x16 mn, mn2, zero16;
    #pragma unroll
    for (int r = 0; r < 16; ++r) { mn[r] = 3.4e38f; mn2[r] = 3.4e38f; zero16[r] = 0.f; }

    int boff = lr * 32 + lh * 16;
    #pragma unroll 2
    for (int ct = 0; ct < 16; ++ct) {
        short8 b0 = *(const short8*)(cands + boff);
        boff += 1024;
        f32x16 a0 = __builtin_amdgcn_mfma_f32_32x32x16_bf16(af[0], b0, zero16, 0,0,0);
        f32x16 a1 = __builtin_amdgcn_mfma_f32_32x32x16_bf16(af[1], b0, zero16, 0,0,0);
        #pragma unroll
        for (int r = 0; r < 16; ++r) mn[r]  = fminf(mn[r],  a0[r]);
        #pragma unroll
        for (int r = 0; r < 16; ++r) mn2[r] = fminf(mn2[r], a1[r]);
    }

    // ---- epilogue: min across 32 candidate-cols; write per-query chunk mins ----
    // D layout: col = lane&31, row = (r&3) + 8*(r>>2) + 4*lh
    float* pmin = ws + (size_t)g * (CC * 256) + cc * 256;
    #pragma unroll
    for (int r = 0; r < 16; ++r) {
        float v = mn[r];
        v = fminf(v, __shfl_xor(v, 1, 64));
        v = fminf(v, __shfl_xor(v, 2, 64));
        v = fminf(v, __shfl_xor(v, 4, 64));
        v = fminf(v, __shfl_xor(v, 8, 64));
        v = fminf(v, __shfl_xor(v, 16, 64));
        if (lr == 0) pmin[(wid*2+0)*32 + ((r&3) + 8*(r>>2) + 4*lh)] = v;
        float w = mn2[r];
        w = fminf(w, __shfl_xor(w, 1, 64));
        w = fminf(w, __shfl_xor(w, 2, 64));
        w = fminf(w, __shfl_xor(w, 4, 64));
        w = fminf(w, __shfl_xor(w, 8, 64));
        w = fminf(w, __shfl_xor(w, 16, 64));
        if (lr == 0) pmin[(wid*2+1)*32 + ((r&3) + 8*(r>>2) + 4*lh)] = w;
    }
}

// ---- kernel 2: min across CC chunks, sum per (dir,batch) -------------------
__global__ __launch_bounds__(256) void combine_kernel(
    const float* __restrict__ ws, float* __restrict__ partial)
{
    const int db  = blockIdx.x;       // 0..63
    const int tid = threadIdx.x;

    float s = 0.f;
    #pragma unroll
    for (int q = 0; q < QC; ++q) {
        const float* gp = ws + ((size_t)db * QC + q) * (CC * 256);
        s += fminf(fminf(gp[tid], gp[256 + tid]),
                   fminf(gp[512 + tid], gp[768 + tid]));
    }
    #pragma unroll
    for (int o = 32; o > 0; o >>= 1) s += __shfl_down(s, o, 64);
    __shared__ float wsum[4];
    const int lane = tid & 63, wid = tid >> 6;
    if (lane == 0) wsum[wid] = s;
    __syncthreads();
    if (tid == 0) partial[db] = (wsum[0] + wsum[1]) + (wsum[2] + wsum[3]);
}

// ---- kernel 3: 64-sum + cross-entropy + output -----------------------------
__global__ __launch_bounds__(64) void finalize_kernel(
    const float* __restrict__ partial, const float* __restrict__ pred,
    const int* __restrict__ gt, float* __restrict__ out)
{
    const int tid = threadIdx.x;
    __shared__ float s_ce[BATCH];

    float v = partial[tid];
    #pragma unroll
    for (int o = 32; o > 0; o >>= 1) v += __shfl_down(v, o, 64);

    if (tid < BATCH) {
        const float* row = pred + tid * NUM_CLASSES;
        float mx = row[0];
        #pragma unroll
        for (int c = 1; c < NUM_CLASSES; ++c) mx = fmaxf(mx, row[c]);
        float se = 0.f;
        #pragma unroll
        for (int c = 0; c < NUM_CLASSES; ++c) se += __expf(row[c] - mx);
        const int lbl = gt[tid];
        s_ce[tid] = -(row[lbl] - mx - __logf(se));
    }
    __syncthreads();

    if (tid == 0) {
        float cd = v / (float)(BATCH * NPTS);
        float ce = 0.f;
        for (int i = 0; i < BATCH; ++i) ce += s_ce[i];
        ce /= (float)BATCH;
        out[0] = 5.f * cd + ce;
        out[1] = cd;
        out[2] = ce;
    }
}

extern "C" void kernel_launch(void* const* d_in, const int* in_sizes, int n_in,
                              void* d_out, int out_size, void* d_ws, size_t ws_size,
                              hipStream_t stream) {
    const float* inst  = (const float*)d_in[0];
    const float* model = (const float*)d_in[1];
    const float* pred  = (const float*)d_in[2];
    const int*   gt    = (const int*)d_in[3];
    float* out = (float*)d_out;
    float* ws  = (float*)d_ws;
    float* partial = ws + PART_OFF;

    chamfer_pass1<<<2 * BATCH * QC * CC, THREADS, 0, stream>>>(inst, model, ws);
    combine_kernel<<<64, 256, 0, stream>>>(ws, partial);
    finalize_kernel<<<1, 64, 0, stream>>>(partial, pred, gt, out);
}